// Round 1
// baseline (1524.408 us; speedup 1.0000x reference)
//
#include <hip/hip_runtime.h>
#include <math.h>

#define PLANE 16384
#define NTOT  33554432u

__device__ __forceinline__ int bitrev6(int x){
  return ((x&1)<<5)|((x&2)<<3)|((x&4)<<1)|((x&8)>>1)|((x&16)>>3)|((x&32)>>5);
}

__device__ __forceinline__ float bperm(int srcLane, float v){
  return __int_as_float(__builtin_amdgcn_ds_bpermute(srcLane<<2, __float_as_int(v)));
}

// 128-point complex FFT across one wave: lane l holds x[l] (v0) and x[l+64] (v1).
// FWD=1: e^{-i...}; FWD=0: e^{+i...} (unnormalized). Natural order on output.
template<int FWD>
__device__ __forceinline__ void fft128(float& v0r, float& v0i, float& v1r, float& v1i, int l){
  const float SGN = FWD ? -3.14159265358979323846f : 3.14159265358979323846f;
  // stage span=64 (within thread)
  {
    float ar = v0r + v1r, ai = v0i + v1i;
    float br = v0r - v1r, bi = v0i - v1i;
    float ang = SGN * (float)l * (1.0f/64.0f);
    float s, c; __sincosf(ang, &s, &c);
    v0r = ar; v0i = ai;
    v1r = br*c - bi*s; v1i = br*s + bi*c;
  }
  #pragma unroll
  for(int h = 32; h >= 1; h >>= 1){
    int hi = l & h;
    int tt = hi ? (l & (h-1)) : 0;
    float ang = SGN * (float)tt / (float)h;
    float s, c; __sincosf(ang, &s, &c);
    float sg = hi ? -1.f : 1.f;
    float o_r = __shfl_xor(v0r, h), o_i = __shfl_xor(v0i, h);
    float dr = o_r + sg*v0r, di = o_i + sg*v0i;
    v0r = dr*c - di*s; v0i = dr*s + di*c;
    o_r = __shfl_xor(v1r, h); o_i = __shfl_xor(v1i, h);
    dr = o_r + sg*v1r; di = o_i + sg*v1i;
    v1r = dr*c - di*s; v1i = dr*s + di*c;
  }
  // bit-reversed -> natural order: X[(bitrev6(L)<<1)|j] sits at (lane L, reg j)
  int L = bitrev6(l >> 1);
  float p0r = bperm(L,   v0r), p0i = bperm(L,   v0i);
  float q0r = bperm(L,   v1r), q0i = bperm(L,   v1i);
  float p1r = bperm(L+1, v0r), p1i = bperm(L+1, v0i);
  float q1r = bperm(L+1, v1r), q1i = bperm(L+1, v1i);
  if(l & 1){ v0r=q0r; v0i=q0i; v1r=q1r; v1i=q1i; }
  else     { v0r=p0r; v0i=p0i; v1r=p1r; v1i=p1i; }
}

// ---------------- kernel 0: fold BN into weights, transpose for coalescing ---
// wb layout (floats): A1t[c][e] at 0 (128*256), A2t[e][o] at 32768 (256*128),
//                     c1[e] at 65536 (256), c2[o] at 65792 (128)
__global__ __launch_bounds__(256) void k_prep(
    const float* __restrict__ w1, const float* __restrict__ b1,
    const float* __restrict__ g1, const float* __restrict__ be1,
    const float* __restrict__ m1, const float* __restrict__ v1,
    const float* __restrict__ w2, const float* __restrict__ b2,
    const float* __restrict__ g2, const float* __restrict__ be2,
    const float* __restrict__ m2, const float* __restrict__ v2,
    float* __restrict__ wb){
  int bid = blockIdx.x, t = threadIdx.x;
  if(bid < 128){
    // A1t row c=bid ; e = t (0..255)
    float s1 = g1[t] * rsqrtf(v1[t] + 1e-5f);
    wb[bid*256 + t] = w1[t*128 + bid] * s1;
    if(bid == 0) wb[65536 + t] = b1[t]*s1 + be1[t] - m1[t]*s1;
  } else {
    int e = bid - 128;           // 0..255
    if(t < 128){
      float s2 = g2[t] * rsqrtf(v2[t] + 1e-5f);
      wb[32768 + e*128 + t] = w2[t*256 + e] * s2;
      if(e == 0) wb[65792 + t] = b2[t]*s2 + be2[t] - m2[t]*s2;
    }
  }
}

// ---------------- kernel 1: forward 2D FFT + fftshift(all axes) + HPF mask ---
// writes Fs[b'][c'][wd][hd] (shifted coords, transposed spatial layout)
__global__ __launch_bounds__(512) void k_fft_fwd(const float* __restrict__ x2,
                                                 float* __restrict__ fre,
                                                 float* __restrict__ fim){
  __shared__ float sRe[32*129];
  __shared__ float sIm[32*129];
  int bid = blockIdx.x;
  int b = bid >> 7, c = bid & 127;
  int tid = threadIdx.x, wv = tid >> 6, l = tid & 63;
  const float* src = x2 + (size_t)(b*128 + c)*PLANE;
  float R0r[16], R0i[16], R1r[16], R1i[16];
  #pragma unroll
  for(int i=0;i<16;i++){
    int r = wv*16 + i;
    float a  = src[r*128 + l];
    float bb = src[r*128 + l + 64];
    float v0r=a, v0i=0.f, v1r=bb, v1i=0.f;
    fft128<1>(v0r,v0i,v1r,v1i,l);
    R0r[i]=v0r; R0i[i]=v0i; R1r[i]=v1r; R1i[i]=v1i;
  }
  int bp = (b + 8) & 15, cp = (c + 64) & 127;
  float* dre = fre + (size_t)(bp*128 + cp)*PLANE;
  float* dim = fim + (size_t)(bp*128 + cp)*PLANE;
  const float SC = 1.0f/128.0f;   // ortho norm for 2D
  for(int s4=0; s4<4; s4++){
    __syncthreads();
    int half = s4 & 1, rg = s4 >> 1;
    if((l >> 5) == half){
      int wq = l & 31;
      #pragma unroll
      for(int i=0;i<16;i++){
        int r = wv*16 + i;
        sRe[wq*129 + r] = rg ? R1r[i] : R0r[i];
        sIm[wq*129 + r] = rg ? R1i[i] : R0i[i];
      }
    }
    __syncthreads();
    #pragma unroll
    for(int q=0;q<4;q++){
      int j = wv*4 + q;
      float v0r = sRe[j*129 + l],      v0i = sIm[j*129 + l];
      float v1r = sRe[j*129 + l + 64], v1i = sIm[j*129 + l + 64];
      fft128<1>(v0r,v0i,v1r,v1i,l);
      int w  = s4*32 + j;
      int wd = w ^ 64;                       // shifted w index
      float dwc = (float)wd - 63.5f;
      float dw2 = dwc*dwc;
      float d0 = (float)l        - 63.5f;    // hd = l
      float d1 = (float)(l + 64) - 63.5f;    // hd = l+64
      float m0 = (d0*d0 + dw2 >= 64.0f) ? SC : 0.0f;
      float m1 = (d1*d1 + dw2 >= 64.0f) ? SC : 0.0f;
      // value with true h = l+64 lands at hd=l; true h = l lands at hd=l+64
      dre[wd*128 + l]      = v1r * m0;
      dim[wd*128 + l]      = v1i * m0;
      dre[wd*128 + l + 64] = v0r * m1;
      dim[wd*128 + l + 64] = v0i * m1;
    }
  }
}

// ---------------- kernel 2: fused conv1+BN+ReLU+conv2+BN + residual (in place)
__global__ __launch_bounds__(256) void k_conv(const float* __restrict__ wb,
                                              float* fre, float* fim){
  __shared__ float xl[128*33];    // [c][p] stride 33
  __shared__ float hl[32*264];    // [r][e] stride 264 (16B-aligned rows)
  int bid = blockIdx.x;
  int branch = bid >> 13;                    // 0: real, 1: imag
  int pidx = (bid & 8191) * 32;
  int b = pidx >> 14;
  int pix0 = pidx & 16383;
  float* base = (branch ? fim : fre) + (size_t)b*2097152 + pix0;
  int t = threadIdx.x;
  #pragma unroll
  for(int ii=0; ii<16; ii++){
    int idx = t + ii*256;
    int c = idx >> 5, p = idx & 31;
    xl[c*33 + p] = base[c*16384 + p];
  }
  __syncthreads();
  {
    int ri = t >> 5;          // rows 4ri..4ri+3
    int ei = t & 31;          // e = 8ei..8ei+7
    float acc[32];
    #pragma unroll
    for(int z=0; z<32; z++) acc[z]=0.f;
    const float* wp = wb + 8*ei;
    for(int k=0;k<128;k++){
      float w8[8];
      *(float4*)&w8[0] = *(const float4*)(wp + k*256);
      *(float4*)&w8[4] = *(const float4*)(wp + k*256 + 4);
      float xv[4];
      #pragma unroll
      for(int m=0;m<4;m++) xv[m] = xl[k*33 + 4*ri + m];
      #pragma unroll
      for(int m=0;m<4;m++)
        #pragma unroll
        for(int j=0;j<8;j++)
          acc[m*8+j] = fmaf(xv[m], w8[j], acc[m*8+j]);
    }
    float c1v[8];
    *(float4*)&c1v[0] = *(const float4*)(wb + 65536 + 8*ei);
    *(float4*)&c1v[4] = *(const float4*)(wb + 65536 + 8*ei + 4);
    #pragma unroll
    for(int m=0;m<4;m++){
      float hrow[8];
      #pragma unroll
      for(int j=0;j<8;j++) hrow[j] = fmaxf(acc[m*8+j] + c1v[j], 0.f);
      *(float4*)&hl[(4*ri+m)*264 + 8*ei]     = *(float4*)&hrow[0];
      *(float4*)&hl[(4*ri+m)*264 + 8*ei + 4] = *(float4*)&hrow[4];
    }
  }
  __syncthreads();
  {
    int ri = t >> 5;          // rows 4ri..4ri+3
    int oi = t & 31;          // o = 4oi..4oi+3
    float acc2[16];
    #pragma unroll
    for(int z=0; z<16; z++) acc2[z]=0.f;
    const float* w2p = wb + 32768 + 4*oi;
    for(int k=0;k<256;k++){
      float w4[4];
      *(float4*)&w4[0] = *(const float4*)(w2p + k*128);
      float hv[4];
      #pragma unroll
      for(int m=0;m<4;m++) hv[m] = hl[(4*ri+m)*264 + k];
      #pragma unroll
      for(int m=0;m<4;m++)
        #pragma unroll
        for(int j=0;j<4;j++)
          acc2[m*4+j] = fmaf(hv[m], w4[j], acc2[m*4+j]);
    }
    float c2v[4];
    *(float4*)&c2v[0] = *(const float4*)(wb + 65792 + 4*oi);
    #pragma unroll
    for(int m=0;m<4;m++){
      int r = 4*ri + m;
      #pragma unroll
      for(int j=0;j<4;j++){
        int o = 4*oi + j;
        xl[o*33 + r] += acc2[m*4+j] + c2v[j];   // residual: + original input
      }
    }
  }
  __syncthreads();
  #pragma unroll
  for(int ii=0; ii<16; ii++){
    int idx = t + ii*256;
    int c = idx >> 5, p = idx & 31;
    base[c*16384 + p] = xl[c*33 + p];
  }
}

// ---------------- kernel 3: inverse 2D FFT + |.| + all three outputs ---------
// NOTE: zre/zim alias out+NTOT / out+2*NTOT. All reads of z happen before the
// first barrier; writes only after it. No __restrict__ on aliased pointers.
__global__ __launch_bounds__(512) void k_ifft_out(const float* zre, const float* zim,
                                                  const float* __restrict__ xin1,
                                                  const float* __restrict__ xin2,
                                                  float* out){
  __shared__ float sRe[32*129];
  __shared__ float sIm[32*129];
  int bid = blockIdx.x;
  int b = bid >> 7, o = bid & 127;
  size_t plane = (size_t)(b*128 + o)*PLANE;
  int tid = threadIdx.x, wv = tid >> 6, l = tid & 63;
  float R0r[16], R0i[16], R1r[16], R1i[16];
  #pragma unroll
  for(int i=0;i<16;i++){
    int r = wv*16 + i;                       // r = wd
    float v0r = zre[plane + r*128 + l],      v0i = zim[plane + r*128 + l];
    float v1r = zre[plane + r*128 + l + 64], v1i = zim[plane + r*128 + l + 64];
    fft128<0>(v0r,v0i,v1r,v1i,l);            // inverse over hd -> spatial n_h
    R0r[i]=v0r; R0i[i]=v0i; R1r[i]=v1r; R1i[i]=v1i;
  }
  const float SC = 1.0f/128.0f;              // ortho norm for 2D inverse
  for(int s4=0; s4<4; s4++){
    __syncthreads();                         // s4=0: all z reads complete first
    int half = s4 & 1, rg = s4 >> 1;
    if((l >> 5) == half){
      int wq = l & 31;
      #pragma unroll
      for(int i=0;i<16;i++){
        int r = wv*16 + i;
        sRe[wq*129 + r] = rg ? R1r[i] : R0r[i];
        sIm[wq*129 + r] = rg ? R1i[i] : R0i[i];
      }
    }
    __syncthreads();
    #pragma unroll
    for(int q=0;q<4;q++){
      int j = wv*4 + q;
      float v0r = sRe[j*129 + l],      v0i = sIm[j*129 + l];
      float v1r = sRe[j*129 + l + 64], v1i = sIm[j*129 + l + 64];
      fft128<0>(v0r,v0i,v1r,v1i,l);          // inverse over wd -> spatial n_w
      int nh = s4*32 + j;
      float h0 = sqrtf(v0r*v0r + v0i*v0i) * SC;
      float h1 = sqrtf(v1r*v1r + v1i*v1i) * SC;
      size_t i0 = plane + (size_t)nh*128 + l, i1 = i0 + 64;
      float u = xin1[i0], v = xin2[i0];
      out[i0] = u*h0 + u;  out[NTOT + i0] = v*h0 + v;  out[2u*NTOT + i0] = h0;
      u = xin1[i1]; v = xin2[i1];
      out[i1] = u*h1 + u;  out[NTOT + i1] = v*h1 + v;  out[2u*NTOT + i1] = h1;
    }
  }
}

extern "C" void kernel_launch(void* const* d_in, const int* in_sizes, int n_in,
                              void* d_out, int out_size, void* d_ws, size_t ws_size,
                              hipStream_t stream){
  (void)in_sizes; (void)n_in; (void)d_ws; (void)ws_size; (void)out_size;
  const float* x1  = (const float*)d_in[0];
  const float* x2  = (const float*)d_in[1];
  const float* w1  = (const float*)d_in[2];
  const float* b1  = (const float*)d_in[3];
  const float* g1  = (const float*)d_in[4];
  const float* be1 = (const float*)d_in[5];
  const float* m1  = (const float*)d_in[6];
  const float* v1  = (const float*)d_in[7];
  const float* w2  = (const float*)d_in[8];
  const float* b2  = (const float*)d_in[9];
  const float* g2  = (const float*)d_in[10];
  const float* be2 = (const float*)d_in[11];
  const float* m2  = (const float*)d_in[12];
  const float* v2  = (const float*)d_in[13];
  float* out = (float*)d_out;
  float* wb  = out;                 // weights live in out1 slot; k3 overwrites later
  float* fre = out + NTOT;          // spectrum real  (aliases out2 slot)
  float* fim = out + 2u*NTOT;       // spectrum imag  (aliases hx slot)
  hipLaunchKernelGGL(k_prep,     dim3(384),   dim3(256), 0, stream,
                     w1,b1,g1,be1,m1,v1,w2,b2,g2,be2,m2,v2, wb);
  hipLaunchKernelGGL(k_fft_fwd,  dim3(2048),  dim3(512), 0, stream, x2, fre, fim);
  hipLaunchKernelGGL(k_conv,     dim3(16384), dim3(256), 0, stream, wb, fre, fim);
  hipLaunchKernelGGL(k_ifft_out, dim3(2048),  dim3(512), 0, stream, fre, fim, x1, x2, out);
}

// Round 2
// 627.142 us; speedup vs baseline: 2.4307x; 2.4307x over previous
//
#include <hip/hip_runtime.h>
#include <math.h>

#define PLANE 16384
#define NTOT  33554432u

typedef __attribute__((ext_vector_type(8))) short short8;
typedef __attribute__((ext_vector_type(4))) float f32x4;

__device__ __forceinline__ short f2bf(float x){
  unsigned u = __float_as_uint(x);
  u = (u + 0x7FFFu + ((u >> 16) & 1u)) >> 16;
  return (short)u;
}

__device__ __forceinline__ int bitrev6(int x){
  return ((x&1)<<5)|((x&2)<<3)|((x&4)<<1)|((x&8)>>1)|((x&16)>>3)|((x&32)>>5);
}

__device__ __forceinline__ float bperm(int srcLane, float v){
  return __int_as_float(__builtin_amdgcn_ds_bpermute(srcLane<<2, __float_as_int(v)));
}

// 128-point complex FFT across one wave: lane l holds x[l] (v0) and x[l+64] (v1).
template<int FWD>
__device__ __forceinline__ void fft128(float& v0r, float& v0i, float& v1r, float& v1i, int l){
  const float SGN = FWD ? -3.14159265358979323846f : 3.14159265358979323846f;
  {
    float ar = v0r + v1r, ai = v0i + v1i;
    float br = v0r - v1r, bi = v0i - v1i;
    float ang = SGN * (float)l * (1.0f/64.0f);
    float s, c; __sincosf(ang, &s, &c);
    v0r = ar; v0i = ai;
    v1r = br*c - bi*s; v1i = br*s + bi*c;
  }
  #pragma unroll
  for(int h = 32; h >= 1; h >>= 1){
    int hi = l & h;
    int tt = hi ? (l & (h-1)) : 0;
    float ang = SGN * (float)tt / (float)h;
    float s, c; __sincosf(ang, &s, &c);
    float sg = hi ? -1.f : 1.f;
    float o_r = __shfl_xor(v0r, h), o_i = __shfl_xor(v0i, h);
    float dr = o_r + sg*v0r, di = o_i + sg*v0i;
    v0r = dr*c - di*s; v0i = dr*s + di*c;
    o_r = __shfl_xor(v1r, h); o_i = __shfl_xor(v1i, h);
    dr = o_r + sg*v1r; di = o_i + sg*v1i;
    v1r = dr*c - di*s; v1i = dr*s + di*c;
  }
  int L = bitrev6(l >> 1);
  float p0r = bperm(L,   v0r), p0i = bperm(L,   v0i);
  float q0r = bperm(L,   v1r), q0i = bperm(L,   v1i);
  float p1r = bperm(L+1, v0r), p1i = bperm(L+1, v0i);
  float q1r = bperm(L+1, v1r), q1i = bperm(L+1, v1i);
  if(l & 1){ v0r=q0r; v0i=q0i; v1r=q1r; v1i=q1i; }
  else     { v0r=p0r; v0i=p0i; v1r=p1r; v1i=p1i; }
}

// ---------------- kernel 0: fold BN, emit MFMA-fragment-packed bf16 weights --
// wb layout: shorts [0,32768)       = w1p  B-frags: [(et*4+kt)*64 + l]*8 + j
//            shorts [32768,65536)   = w2p  A-frags: [(ot*8+kt)*64 + l]*8 + j
//            floats [32768,33024)   = c1[256]
//            floats [33024,33152)   = c2[128]
__global__ __launch_bounds__(256) void k_prep(
    const float* __restrict__ w1, const float* __restrict__ b1,
    const float* __restrict__ g1, const float* __restrict__ be1,
    const float* __restrict__ m1, const float* __restrict__ v1,
    const float* __restrict__ w2, const float* __restrict__ b2,
    const float* __restrict__ g2, const float* __restrict__ be2,
    const float* __restrict__ m2, const float* __restrict__ v2,
    float* __restrict__ wb){
  int g = blockIdx.x*256 + threadIdx.x;      // 65536 threads
  short* wbs = (short*)wb;
  if(g < 32768){
    // W1eff B-fragment: k = channel c, col = e
    int kt = (g >> 9) & 3, l = (g >> 3) & 63, j = g & 7;
    int et = g >> 11;
    int c = kt*32 + 8*(l>>4) + j;
    int e = et*16 + (l&15);
    float s1 = g1[e]*rsqrtf(v1[e]+1e-5f);
    wbs[g] = f2bf(w1[e*128 + c]*s1);
  } else {
    // W2eff A-fragment: row = o, k = e
    int g2i = g - 32768;
    int ot = g2i >> 12, kt = (g2i >> 9) & 7, l = (g2i >> 3) & 63, j = g2i & 7;
    int o = ot*16 + (l&15);
    int e = kt*32 + 8*(l>>4) + j;
    float s2 = g2[o]*rsqrtf(v2[o]+1e-5f);
    wbs[32768 + g2i] = f2bf(w2[o*256 + e]*s2);
  }
  if(g < 256){
    float s1 = g1[g]*rsqrtf(v1[g]+1e-5f);
    wb[32768 + g] = b1[g]*s1 + be1[g] - m1[g]*s1;
  }
  if(g < 128){
    float s2 = g2[g]*rsqrtf(v2[g]+1e-5f);
    wb[33024 + g] = b2[g]*s2 + be2[g] - m2[g]*s2;
  }
}

// ---------------- kernel 1: forward 2D FFT + fftshift(all axes) + HPF mask ---
__global__ __launch_bounds__(512) void k_fft_fwd(const float* __restrict__ x2,
                                                 float* __restrict__ fre,
                                                 float* __restrict__ fim){
  __shared__ float sRe[32*129];
  __shared__ float sIm[32*129];
  int bid = blockIdx.x;
  int b = bid >> 7, c = bid & 127;
  int tid = threadIdx.x, wv = tid >> 6, l = tid & 63;
  const float* src = x2 + (size_t)(b*128 + c)*PLANE;
  float R0r[16], R0i[16], R1r[16], R1i[16];
  #pragma unroll
  for(int i=0;i<16;i++){
    int r = wv*16 + i;
    float a  = src[r*128 + l];
    float bb = src[r*128 + l + 64];
    float v0r=a, v0i=0.f, v1r=bb, v1i=0.f;
    fft128<1>(v0r,v0i,v1r,v1i,l);
    R0r[i]=v0r; R0i[i]=v0i; R1r[i]=v1r; R1i[i]=v1i;
  }
  int bp = (b + 8) & 15, cp = (c + 64) & 127;
  float* dre = fre + (size_t)(bp*128 + cp)*PLANE;
  float* dim = fim + (size_t)(bp*128 + cp)*PLANE;
  const float SC = 1.0f/128.0f;
  for(int s4=0; s4<4; s4++){
    __syncthreads();
    int half = s4 & 1, rg = s4 >> 1;
    if((l >> 5) == half){
      int wq = l & 31;
      #pragma unroll
      for(int i=0;i<16;i++){
        int r = wv*16 + i;
        sRe[wq*129 + r] = rg ? R1r[i] : R0r[i];
        sIm[wq*129 + r] = rg ? R1i[i] : R0i[i];
      }
    }
    __syncthreads();
    #pragma unroll
    for(int q=0;q<4;q++){
      int j = wv*4 + q;
      float v0r = sRe[j*129 + l],      v0i = sIm[j*129 + l];
      float v1r = sRe[j*129 + l + 64], v1i = sIm[j*129 + l + 64];
      fft128<1>(v0r,v0i,v1r,v1i,l);
      int w  = s4*32 + j;
      int wd = w ^ 64;
      float dwc = (float)wd - 63.5f;
      float dw2 = dwc*dwc;
      float d0 = (float)l        - 63.5f;
      float d1 = (float)(l + 64) - 63.5f;
      float m0 = (d0*d0 + dw2 >= 64.0f) ? SC : 0.0f;
      float m1 = (d1*d1 + dw2 >= 64.0f) ? SC : 0.0f;
      dre[wd*128 + l]      = v1r * m0;
      dim[wd*128 + l]      = v1i * m0;
      dre[wd*128 + l + 64] = v0r * m1;
      dim[wd*128 + l + 64] = v0i * m1;
    }
  }
}

// ---------------- kernel 2: fused 1x1conv chain via bf16 MFMA, in place ------
// Per block: 64 pixels x all 128 channels. GEMM1: H[64p][256e], GEMM2 computes
// D[o][p] directly (A=W2 rows=o) so the global write is coalesced.
#define XPITCH 136   // shorts; 272B = 17*16B (odd) -> conflict-free b128
#define EPITCH 264   // shorts; 528B = 33*16B (odd) -> conflict-free b128
__global__ __launch_bounds__(256,3) void k_conv(const float* __restrict__ wb,
                                                float* fre, float* fim){
  __shared__ short xs[64*XPITCH];
  __shared__ short hs[64*EPITCH];
  const short* wbs = (const short*)wb;
  int bid = blockIdx.x;
  int branch = bid >> 12;               // 0: real, 1: imag
  int rem = bid & 4095;
  int b = rem >> 8;
  int pix0 = (rem & 255) * 64;
  float* base = (branch ? fim : fre) + (size_t)b*2097152 + pix0;
  int t = threadIdx.x, l = t & 63, w = t >> 6;

  // ---- stage X -> LDS bf16, xs[p][c] ----
  #pragma unroll
  for(int k=0;k<4;k++){
    float fb[8];
    #pragma unroll
    for(int j=0;j<8;j++) fb[j] = base[(size_t)(w*32 + k*8 + j)*PLANE + l];
    short8 v;
    #pragma unroll
    for(int j=0;j<8;j++) v[j] = f2bf(fb[j]);
    *(short8*)(xs + l*XPITCH + w*32 + k*8) = v;
  }

  // ---- GEMM1 weights + bias to regs (global, L2-hot) ----
  short8 bw1[4][4];
  #pragma unroll
  for(int et=0; et<4; et++)
    #pragma unroll
    for(int kt=0; kt<4; kt++)
      bw1[et][kt] = *(const short8*)(wbs + (((w*4+et)*4 + kt)*64 + l)*8);
  float c1v[4];
  #pragma unroll
  for(int et=0; et<4; et++) c1v[et] = wb[32768 + w*64 + et*16 + (l&15)];

  __syncthreads();

  // ---- GEMM1: H = relu(X*W1 + c1), wave w owns e in [w*64, w*64+64) ----
  #pragma unroll
  for(int mt=0; mt<4; mt++){
    short8 xa[4];
    #pragma unroll
    for(int kt=0; kt<4; kt++)
      xa[kt] = *(const short8*)(xs + (mt*16 + (l&15))*XPITCH + kt*32 + 8*(l>>4));
    f32x4 a0 = {0,0,0,0}, a1 = {0,0,0,0}, a2 = {0,0,0,0}, a3 = {0,0,0,0};
    #pragma unroll
    for(int kt=0; kt<4; kt++){
      a0 = __builtin_amdgcn_mfma_f32_16x16x32_bf16(xa[kt], bw1[0][kt], a0, 0,0,0);
      a1 = __builtin_amdgcn_mfma_f32_16x16x32_bf16(xa[kt], bw1[1][kt], a1, 0,0,0);
      a2 = __builtin_amdgcn_mfma_f32_16x16x32_bf16(xa[kt], bw1[2][kt], a2, 0,0,0);
      a3 = __builtin_amdgcn_mfma_f32_16x16x32_bf16(xa[kt], bw1[3][kt], a3, 0,0,0);
    }
    #pragma unroll
    for(int et=0; et<4; et++){
      f32x4 av = et==0?a0 : et==1?a1 : et==2?a2 : a3;
      #pragma unroll
      for(int r=0; r<4; r++){
        float h = fmaxf(av[r] + c1v[et], 0.f);
        hs[(mt*16 + (l>>4)*4 + r)*EPITCH + w*64 + et*16 + (l&15)] = f2bf(h);
      }
    }
  }

  // ---- GEMM2 weights + bias to regs ----
  short8 aw2[2][8];
  #pragma unroll
  for(int ot=0; ot<2; ot++)
    #pragma unroll
    for(int kt=0; kt<8; kt++)
      aw2[ot][kt] = *(const short8*)(wbs + 32768 + (((w*2+ot)*8 + kt)*64 + l)*8);
  float c2r[8];
  #pragma unroll
  for(int ot=0; ot<2; ot++)
    #pragma unroll
    for(int r=0; r<4; r++)
      c2r[ot*4+r] = wb[33024 + w*32 + ot*16 + (l>>4)*4 + r];

  __syncthreads();

  // ---- GEMM2: D[o][p] = W2*H^T, + c2 + residual, wave w owns o in [w*32,+32) -
  #pragma unroll
  for(int pt=0; pt<4; pt++){
    short8 hb[8];
    #pragma unroll
    for(int kt=0; kt<8; kt++)
      hb[kt] = *(const short8*)(hs + (pt*16 + (l&15))*EPITCH + kt*32 + 8*(l>>4));
    f32x4 d0 = {0,0,0,0}, d1 = {0,0,0,0};
    #pragma unroll
    for(int kt=0; kt<8; kt++){
      d0 = __builtin_amdgcn_mfma_f32_16x16x32_bf16(aw2[0][kt], hb[kt], d0, 0,0,0);
      d1 = __builtin_amdgcn_mfma_f32_16x16x32_bf16(aw2[1][kt], hb[kt], d1, 0,0,0);
    }
    #pragma unroll
    for(int ot=0; ot<2; ot++){
      f32x4 dv = ot==0 ? d0 : d1;
      #pragma unroll
      for(int r=0; r<4; r++){
        int o = w*32 + ot*16 + (l>>4)*4 + r;
        size_t gi = (size_t)o*PLANE + pt*16 + (l&15);
        base[gi] = base[gi] + dv[r] + c2r[ot*4+r];   // residual + bias
      }
    }
  }
}

// ---------------- kernel 3: inverse 2D FFT + |.| + all three outputs ---------
__global__ __launch_bounds__(512) void k_ifft_out(const float* zre, const float* zim,
                                                  const float* __restrict__ xin1,
                                                  const float* __restrict__ xin2,
                                                  float* out){
  __shared__ float sRe[32*129];
  __shared__ float sIm[32*129];
  int bid = blockIdx.x;
  int b = bid >> 7, o = bid & 127;
  size_t plane = (size_t)(b*128 + o)*PLANE;
  int tid = threadIdx.x, wv = tid >> 6, l = tid & 63;
  float R0r[16], R0i[16], R1r[16], R1i[16];
  #pragma unroll
  for(int i=0;i<16;i++){
    int r = wv*16 + i;
    float v0r = zre[plane + r*128 + l],      v0i = zim[plane + r*128 + l];
    float v1r = zre[plane + r*128 + l + 64], v1i = zim[plane + r*128 + l + 64];
    fft128<0>(v0r,v0i,v1r,v1i,l);
    R0r[i]=v0r; R0i[i]=v0i; R1r[i]=v1r; R1i[i]=v1i;
  }
  const float SC = 1.0f/128.0f;
  for(int s4=0; s4<4; s4++){
    __syncthreads();
    int half = s4 & 1, rg = s4 >> 1;
    if((l >> 5) == half){
      int wq = l & 31;
      #pragma unroll
      for(int i=0;i<16;i++){
        int r = wv*16 + i;
        sRe[wq*129 + r] = rg ? R1r[i] : R0r[i];
        sIm[wq*129 + r] = rg ? R1i[i] : R0i[i];
      }
    }
    __syncthreads();
    #pragma unroll
    for(int q=0;q<4;q++){
      int j = wv*4 + q;
      float v0r = sRe[j*129 + l],      v0i = sIm[j*129 + l];
      float v1r = sRe[j*129 + l + 64], v1i = sIm[j*129 + l + 64];
      fft128<0>(v0r,v0i,v1r,v1i,l);
      int nh = s4*32 + j;
      float h0 = sqrtf(v0r*v0r + v0i*v0i) * SC;
      float h1 = sqrtf(v1r*v1r + v1i*v1i) * SC;
      size_t i0 = plane + (size_t)nh*128 + l, i1 = i0 + 64;
      float u = xin1[i0], v = xin2[i0];
      out[i0] = u*h0 + u;  out[NTOT + i0] = v*h0 + v;  out[2u*NTOT + i0] = h0;
      u = xin1[i1]; v = xin2[i1];
      out[i1] = u*h1 + u;  out[NTOT + i1] = v*h1 + v;  out[2u*NTOT + i1] = h1;
    }
  }
}

extern "C" void kernel_launch(void* const* d_in, const int* in_sizes, int n_in,
                              void* d_out, int out_size, void* d_ws, size_t ws_size,
                              hipStream_t stream){
  (void)in_sizes; (void)n_in; (void)d_ws; (void)ws_size; (void)out_size;
  const float* x1  = (const float*)d_in[0];
  const float* x2  = (const float*)d_in[1];
  const float* w1  = (const float*)d_in[2];
  const float* b1  = (const float*)d_in[3];
  const float* g1  = (const float*)d_in[4];
  const float* be1 = (const float*)d_in[5];
  const float* m1  = (const float*)d_in[6];
  const float* v1  = (const float*)d_in[7];
  const float* w2  = (const float*)d_in[8];
  const float* b2  = (const float*)d_in[9];
  const float* g2  = (const float*)d_in[10];
  const float* be2 = (const float*)d_in[11];
  const float* m2  = (const float*)d_in[12];
  const float* v2  = (const float*)d_in[13];
  float* out = (float*)d_out;
  float* wb  = out;                 // packed weights live in out1 slot until k_ifft_out
  float* fre = out + NTOT;          // spectrum real  (aliases out2 slot)
  float* fim = out + 2u*NTOT;       // spectrum imag  (aliases hx slot)
  hipLaunchKernelGGL(k_prep,     dim3(256),   dim3(256), 0, stream,
                     w1,b1,g1,be1,m1,v1,w2,b2,g2,be2,m2,v2, wb);
  hipLaunchKernelGGL(k_fft_fwd,  dim3(2048),  dim3(512), 0, stream, x2, fre, fim);
  hipLaunchKernelGGL(k_conv,     dim3(8192),  dim3(256), 0, stream, wb, fre, fim);
  hipLaunchKernelGGL(k_ifft_out, dim3(2048),  dim3(512), 0, stream, fre, fim, x1, x2, out);
}

// Round 3
// 517.333 us; speedup vs baseline: 2.9467x; 1.2123x over previous
//
#include <hip/hip_runtime.h>
#include <math.h>

#define PLANE 16384
#define NTOT  33554432u
typedef unsigned int  uint;
typedef unsigned short ushort;

typedef __attribute__((ext_vector_type(8))) short short8;
typedef __attribute__((ext_vector_type(8))) ushort ushort8;
typedef __attribute__((ext_vector_type(4))) float f32x4;

__device__ __forceinline__ ushort f2bf(float x){
  unsigned u = __float_as_uint(x);
  u = (u + 0x7FFFu + ((u >> 16) & 1u)) >> 16;
  return (ushort)u;
}
__device__ __forceinline__ float bf2f(ushort h){
  return __uint_as_float(((uint)h) << 16);
}
__device__ __forceinline__ uint pk(float a, float b){
  return (uint)f2bf(a) | ((uint)f2bf(b) << 16);
}

__device__ __forceinline__ int bitrev6(int x){
  return ((x&1)<<5)|((x&2)<<3)|((x&4)<<1)|((x&8)>>1)|((x&16)>>3)|((x&32)>>5);
}
__device__ __forceinline__ int rev4(int m){
  return ((m&1)<<3)|((m&2)<<1)|((m&4)>>1)|((m&8)>>3);
}
__device__ __forceinline__ float bperm(int srcLane, float v){
  return __int_as_float(__builtin_amdgcn_ds_bpermute(srcLane<<2, __float_as_int(v)));
}

// 128-point complex FFT across one wave: lane l holds x[l] (v0) and x[l+64] (v1).
// PERM=1: natural order out (v0=X[l], v1=X[l+64]).
// PERM=0: bit-reversed out: lane l holds X[2*bitrev6(l)] (v0), X[2*bitrev6(l)+1] (v1).
template<int FWD, int PERM>
__device__ __forceinline__ void fft128(float& v0r, float& v0i, float& v1r, float& v1i, int l){
  const float SGN = FWD ? -3.14159265358979323846f : 3.14159265358979323846f;
  {
    float ar = v0r + v1r, ai = v0i + v1i;
    float br = v0r - v1r, bi = v0i - v1i;
    float ang = SGN * (float)l * (1.0f/64.0f);
    float s, c; __sincosf(ang, &s, &c);
    v0r = ar; v0i = ai;
    v1r = br*c - bi*s; v1i = br*s + bi*c;
  }
  #pragma unroll
  for(int h = 32; h >= 1; h >>= 1){
    int hi = l & h;
    int tt = hi ? (l & (h-1)) : 0;
    float ang = SGN * (float)tt / (float)h;
    float s, c; __sincosf(ang, &s, &c);
    float sg = hi ? -1.f : 1.f;
    float o_r = __shfl_xor(v0r, h), o_i = __shfl_xor(v0i, h);
    float dr = o_r + sg*v0r, di = o_i + sg*v0i;
    v0r = dr*c - di*s; v0i = dr*s + di*c;
    o_r = __shfl_xor(v1r, h); o_i = __shfl_xor(v1i, h);
    dr = o_r + sg*v1r; di = o_i + sg*v1i;
    v1r = dr*c - di*s; v1i = dr*s + di*c;
  }
  if(PERM){
    int L = bitrev6(l >> 1);
    float p0r = bperm(L,   v0r), p0i = bperm(L,   v0i);
    float q0r = bperm(L,   v1r), q0i = bperm(L,   v1i);
    float p1r = bperm(L+1, v0r), p1i = bperm(L+1, v0i);
    float q1r = bperm(L+1, v1r), q1i = bperm(L+1, v1i);
    if(l & 1){ v0r=q0r; v0i=q0i; v1r=q1r; v1i=q1i; }
    else     { v0r=p0r; v0i=p0i; v1r=p1r; v1i=p1i; }
  }
}

// ---------------- kernel 0: fold BN, emit MFMA-fragment-packed bf16 weights --
// wb layout: shorts [0,32768)     = w1p B-frags: [(et*4+kt)*64 + l]*8 + j
//            shorts [32768,65536) = w2p A-frags: [(ot*8+kt)*64 + l]*8 + j
//            floats [32768,33024) = c1[256]; floats [33024,33152) = c2[128]
__global__ __launch_bounds__(256) void k_prep(
    const float* __restrict__ w1, const float* __restrict__ b1,
    const float* __restrict__ g1, const float* __restrict__ be1,
    const float* __restrict__ m1, const float* __restrict__ v1,
    const float* __restrict__ w2, const float* __restrict__ b2,
    const float* __restrict__ g2, const float* __restrict__ be2,
    const float* __restrict__ m2, const float* __restrict__ v2,
    float* __restrict__ wb){
  int g = blockIdx.x*256 + threadIdx.x;      // 65536 threads
  ushort* wbs = (ushort*)wb;
  if(g < 32768){
    int kt = (g >> 9) & 3, l = (g >> 3) & 63, j = g & 7;
    int et = g >> 11;
    int c = kt*32 + 8*(l>>4) + j;
    int e = et*16 + (l&15);
    float s1 = g1[e]*rsqrtf(v1[e]+1e-5f);
    wbs[g] = f2bf(w1[e*128 + c]*s1);
  } else {
    int g2i = g - 32768;
    int ot = g2i >> 12, kt = (g2i >> 9) & 7, l = (g2i >> 3) & 63, j = g2i & 7;
    int o = ot*16 + (l&15);
    int e = kt*32 + 8*(l>>4) + j;
    float s2 = g2[o]*rsqrtf(v2[o]+1e-5f);
    wbs[32768 + g2i] = f2bf(w2[o*256 + e]*s2);
  }
  if(g < 256){
    float s1 = g1[g]*rsqrtf(v1[g]+1e-5f);
    wb[32768 + g] = b1[g]*s1 + be1[g] - m1[g]*s1;
  }
  if(g < 128){
    float s2 = g2[g]*rsqrtf(v2[g]+1e-5f);
    wb[33024 + g] = b2[g]*s2 + be2[g] - m2[g]*s2;
  }
}

// ---------------- kernel 1: forward 2D FFT + fftshift + HPF mask -> bf16 -----
// writes spec[b'][c'][wd][hd] as packed (re,im) bf16 dwords
__global__ __launch_bounds__(512) void k_fft_fwd(const float* __restrict__ x2,
                                                 uint* __restrict__ spec){
  __shared__ float sRe[32*129];
  __shared__ float sIm[32*129];
  int bid = blockIdx.x;
  int b = bid >> 7, c = bid & 127;
  int tid = threadIdx.x, wv = tid >> 6, l = tid & 63;
  const float* src = x2 + (size_t)(b*128 + c)*PLANE;
  float R0r[16], R0i[16], R1r[16], R1i[16];
  #pragma unroll
  for(int i=0;i<16;i++){
    int r = wv*16 + i;
    float a  = src[r*128 + l];
    float bb = src[r*128 + l + 64];
    float v0r=a, v0i=0.f, v1r=bb, v1i=0.f;
    fft128<1,0>(v0r,v0i,v1r,v1i,l);           // bit-reversed out, no bperm
    R0r[i]=v0r; R0i[i]=v0i; R1r[i]=v1r; R1i[i]=v1i;
  }
  int bp = (b + 8) & 15, cp = (c + 64) & 127;
  uint* dst = spec + (size_t)(bp*128 + cp)*PLANE;
  const float SC = 1.0f/128.0f;
  int wq = rev4(l>>2) << 1;
  for(int s4=0; s4<4; s4++){
    __syncthreads();
    int r2 = ((s4&1)<<1) | ((s4>>1)&1);       // lanes owning this pass's columns
    if((l&3) == r2){
      #pragma unroll
      for(int i=0;i<16;i++){
        int r = wv*16 + i;
        sRe[wq*129 + r]     = R0r[i];  sIm[wq*129 + r]     = R0i[i];
        sRe[(wq+1)*129 + r] = R1r[i];  sIm[(wq+1)*129 + r] = R1i[i];
      }
    }
    __syncthreads();
    #pragma unroll
    for(int q=0;q<4;q++){
      int j = wv*4 + q;
      float v0r = sRe[j*129 + l],      v0i = sIm[j*129 + l];
      float v1r = sRe[j*129 + l + 64], v1i = sIm[j*129 + l + 64];
      fft128<1,1>(v0r,v0i,v1r,v1i,l);
      int w  = s4*32 + j;
      int wd = w ^ 64;
      float dwc = (float)wd - 63.5f;
      float dw2 = dwc*dwc;
      float d0 = (float)l        - 63.5f;
      float d1 = (float)(l + 64) - 63.5f;
      float m0 = (d0*d0 + dw2 >= 64.0f) ? SC : 0.0f;
      float m1 = (d1*d1 + dw2 >= 64.0f) ? SC : 0.0f;
      dst[wd*128 + l]      = pk(v1r*m0, v1i*m0);
      dst[wd*128 + l + 64] = pk(v0r*m1, v0i*m1);
    }
  }
}

// ---------------- kernel 2: fused 1x1conv chain via bf16 MFMA ----------------
// Block: 32 pixels x 2 parts (re,im) = 64 GEMM rows, all 128 channels.
// reads bf16 spec (slot1), writes bf16 z (slot2). No RMW.
#define XPITCH 136   // shorts; 272B = 17*16B -> b128-aligned rows
#define EPITCH 264   // shorts; 528B = 33*16B
__global__ __launch_bounds__(256,3) void k_conv(const float* __restrict__ wb,
                                                const uint* __restrict__ spec,
                                                uint* __restrict__ zo){
  __shared__ ushort xs[64*XPITCH];   // rows: p (re) / 32+p (im), cols: channel
  __shared__ ushort hs[64*EPITCH];
  const ushort* wbs = (const ushort*)wb;
  int bid = blockIdx.x;
  int b = bid >> 9;
  int pix0 = (bid & 511) * 32;
  const uint* sp = spec + (size_t)(b*128)*PLANE + pix0;
  int t = threadIdx.x, l = t & 63, w = t >> 6;

  // ---- stage spectrum -> LDS (split re/im into rows p / p+32) ----
  {
    int p = t & 31, g = t >> 5;           // g in 0..7: channel group
    #pragma unroll
    for(int half=0; half<2; half++){
      ushort re8[8], im8[8];
      #pragma unroll
      for(int k=0;k<8;k++){
        uint u = sp[(size_t)(g*16 + half*8 + k)*PLANE + p];
        re8[k] = (ushort)u; im8[k] = (ushort)(u>>16);
      }
      *(ushort8*)(xs + p*XPITCH      + g*16 + half*8) = *(ushort8*)re8;
      *(ushort8*)(xs + (p+32)*XPITCH + g*16 + half*8) = *(ushort8*)im8;
    }
  }

  // ---- GEMM1 weights + bias to regs ----
  short8 bw1[4][4];
  #pragma unroll
  for(int et=0; et<4; et++)
    #pragma unroll
    for(int kt=0; kt<4; kt++)
      bw1[et][kt] = *(const short8*)(wbs + (((w*4+et)*4 + kt)*64 + l)*8);
  float c1v[4];
  #pragma unroll
  for(int et=0; et<4; et++) c1v[et] = wb[32768 + w*64 + et*16 + (l&15)];

  __syncthreads();

  // ---- GEMM1: H = relu(X*W1 + c1); wave w owns e in [w*64, w*64+64) ----
  #pragma unroll
  for(int mt=0; mt<4; mt++){
    short8 xa[4];
    #pragma unroll
    for(int kt=0; kt<4; kt++)
      xa[kt] = *(const short8*)(xs + (mt*16 + (l&15))*XPITCH + kt*32 + 8*(l>>4));
    f32x4 a0 = {0,0,0,0}, a1 = {0,0,0,0}, a2 = {0,0,0,0}, a3 = {0,0,0,0};
    #pragma unroll
    for(int kt=0; kt<4; kt++){
      a0 = __builtin_amdgcn_mfma_f32_16x16x32_bf16(xa[kt], bw1[0][kt], a0, 0,0,0);
      a1 = __builtin_amdgcn_mfma_f32_16x16x32_bf16(xa[kt], bw1[1][kt], a1, 0,0,0);
      a2 = __builtin_amdgcn_mfma_f32_16x16x32_bf16(xa[kt], bw1[2][kt], a2, 0,0,0);
      a3 = __builtin_amdgcn_mfma_f32_16x16x32_bf16(xa[kt], bw1[3][kt], a3, 0,0,0);
    }
    #pragma unroll
    for(int et=0; et<4; et++){
      f32x4 av = et==0?a0 : et==1?a1 : et==2?a2 : a3;
      #pragma unroll
      for(int r=0; r<4; r++){
        float h = fmaxf(av[r] + c1v[et], 0.f);
        hs[(mt*16 + (l>>4)*4 + r)*EPITCH + w*64 + et*16 + (l&15)] = f2bf(h);
      }
    }
  }

  // ---- GEMM2 weights + bias to regs ----
  short8 aw2[2][8];
  #pragma unroll
  for(int ot=0; ot<2; ot++)
    #pragma unroll
    for(int kt=0; kt<8; kt++)
      aw2[ot][kt] = *(const short8*)(wbs + 32768 + (((w*2+ot)*8 + kt)*64 + l)*8);
  float c2r[8];
  #pragma unroll
  for(int ot=0; ot<2; ot++)
    #pragma unroll
    for(int r=0; r<4; r++)
      c2r[ot*4+r] = wb[33024 + w*32 + ot*16 + (l>>4)*4 + r];

  __syncthreads();

  // ---- GEMM2: D[o][row] = W2*H^T; wave w owns o in [w*32, w*32+32) ----
  f32x4 d[2][4];
  #pragma unroll
  for(int ot=0; ot<2; ot++)
    #pragma unroll
    for(int pt=0; pt<4; pt++) d[ot][pt] = (f32x4){0,0,0,0};
  for(int kt=0; kt<8; kt++){
    short8 hb[4];
    #pragma unroll
    for(int pt=0; pt<4; pt++)
      hb[pt] = *(const short8*)(hs + (pt*16 + (l&15))*EPITCH + kt*32 + 8*(l>>4));
    #pragma unroll
    for(int ot=0; ot<2; ot++)
      #pragma unroll
      for(int pt=0; pt<4; pt++)
        d[ot][pt] = __builtin_amdgcn_mfma_f32_16x16x32_bf16(aw2[ot][kt], hb[pt], d[ot][pt], 0,0,0);
  }

  // ---- epilogue: + c2 + residual(bf16 input), pack (re,im) -> dword store ----
  uint* zb = zo + (size_t)(b*128)*PLANE + pix0;
  #pragma unroll
  for(int ot=0; ot<2; ot++){
    #pragma unroll
    for(int pp=0; pp<2; pp++){
      #pragma unroll
      for(int r=0; r<4; r++){
        int o = w*32 + ot*16 + (l>>4)*4 + r;
        int p = pp*16 + (l&15);
        float re = d[ot][pp][r]   + c2r[ot*4+r] + bf2f(xs[p*XPITCH + o]);
        float im = d[ot][pp+2][r] + c2r[ot*4+r] + bf2f(xs[(p+32)*XPITCH + o]);
        zb[(size_t)o*PLANE + p] = pk(re, im);
      }
    }
  }
}

// ---------------- kernel 3: inverse 2D FFT + |.| + all three outputs ---------
// z (bf16 packed) aliases out+2*NTOT; block reads its plane before writing.
__global__ __launch_bounds__(512) void k_ifft_out(const uint* z,
                                                  const float* __restrict__ xin1,
                                                  const float* __restrict__ xin2,
                                                  float* out){
  __shared__ float sRe[32*129];
  __shared__ float sIm[32*129];
  int bid = blockIdx.x;
  int b = bid >> 7, o = bid & 127;
  size_t plane = (size_t)(b*128 + o)*PLANE;
  const uint* zp = z + plane;
  int tid = threadIdx.x, wv = tid >> 6, l = tid & 63;
  float R0r[16], R0i[16], R1r[16], R1i[16];
  #pragma unroll
  for(int i=0;i<16;i++){
    int r = wv*16 + i;
    uint u0 = zp[r*128 + l], u1 = zp[r*128 + l + 64];
    float v0r = bf2f((ushort)u0), v0i = bf2f((ushort)(u0>>16));
    float v1r = bf2f((ushort)u1), v1i = bf2f((ushort)(u1>>16));
    fft128<0,0>(v0r,v0i,v1r,v1i,l);           // bit-reversed out, no bperm
    R0r[i]=v0r; R0i[i]=v0i; R1r[i]=v1r; R1i[i]=v1i;
  }
  const float SC = 1.0f/128.0f;
  int wq = rev4(l>>2) << 1;
  for(int s4=0; s4<4; s4++){
    __syncthreads();                           // s4=0: all z reads complete first
    int r2 = ((s4&1)<<1) | ((s4>>1)&1);
    if((l&3) == r2){
      #pragma unroll
      for(int i=0;i<16;i++){
        int r = wv*16 + i;
        sRe[wq*129 + r]     = R0r[i];  sIm[wq*129 + r]     = R0i[i];
        sRe[(wq+1)*129 + r] = R1r[i];  sIm[(wq+1)*129 + r] = R1i[i];
      }
    }
    __syncthreads();
    #pragma unroll
    for(int q=0;q<4;q++){
      int j = wv*4 + q;
      float v0r = sRe[j*129 + l],      v0i = sIm[j*129 + l];
      float v1r = sRe[j*129 + l + 64], v1i = sIm[j*129 + l + 64];
      fft128<0,1>(v0r,v0i,v1r,v1i,l);
      int nh = s4*32 + j;
      float h0 = sqrtf(v0r*v0r + v0i*v0i) * SC;
      float h1 = sqrtf(v1r*v1r + v1i*v1i) * SC;
      size_t i0 = plane + (size_t)nh*128 + l, i1 = i0 + 64;
      float u = xin1[i0], v = xin2[i0];
      out[i0] = u*h0 + u;  out[NTOT + i0] = v*h0 + v;  out[2u*NTOT + i0] = h0;
      u = xin1[i1]; v = xin2[i1];
      out[i1] = u*h1 + u;  out[NTOT + i1] = v*h1 + v;  out[2u*NTOT + i1] = h1;
    }
  }
}

extern "C" void kernel_launch(void* const* d_in, const int* in_sizes, int n_in,
                              void* d_out, int out_size, void* d_ws, size_t ws_size,
                              hipStream_t stream){
  (void)in_sizes; (void)n_in; (void)d_ws; (void)ws_size; (void)out_size;
  const float* x1  = (const float*)d_in[0];
  const float* x2  = (const float*)d_in[1];
  const float* w1  = (const float*)d_in[2];
  const float* b1  = (const float*)d_in[3];
  const float* g1  = (const float*)d_in[4];
  const float* be1 = (const float*)d_in[5];
  const float* m1  = (const float*)d_in[6];
  const float* v1  = (const float*)d_in[7];
  const float* w2  = (const float*)d_in[8];
  const float* b2  = (const float*)d_in[9];
  const float* g2  = (const float*)d_in[10];
  const float* be2 = (const float*)d_in[11];
  const float* m2  = (const float*)d_in[12];
  const float* v2  = (const float*)d_in[13];
  float* out = (float*)d_out;
  float* wb   = out;                       // slot0: weights (dead once ifft writes out1)
  uint*  spec = (uint*)(out + NTOT);       // slot1: bf16 spectrum (dead once ifft writes out2)
  uint*  z    = (uint*)(out + 2u*NTOT);    // slot2: bf16 z, plane-aliased with hx
  hipLaunchKernelGGL(k_prep,     dim3(256),  dim3(256), 0, stream,
                     w1,b1,g1,be1,m1,v1,w2,b2,g2,be2,m2,v2, wb);
  hipLaunchKernelGGL(k_fft_fwd,  dim3(2048), dim3(512), 0, stream, x2, spec);
  hipLaunchKernelGGL(k_conv,     dim3(8192), dim3(256), 0, stream, wb, spec, z);
  hipLaunchKernelGGL(k_ifft_out, dim3(2048), dim3(512), 0, stream, z, x1, x2, out);
}

// Round 5
// 426.081 us; speedup vs baseline: 3.5777x; 1.2142x over previous
//
#include <hip/hip_runtime.h>
#include <math.h>

#define PLANE 16384
#define NTOT  33554432u
#define TP    136            // LDS row pitch in shorts: 272B = 17*16B -> 2-way max
typedef unsigned int  uint;
typedef unsigned short ushort;

typedef __attribute__((ext_vector_type(8))) short  short8;
typedef __attribute__((ext_vector_type(8))) ushort ushort8;
typedef __attribute__((ext_vector_type(4))) ushort bf16x4;
typedef __attribute__((ext_vector_type(4))) uint   u32x4;
typedef __attribute__((ext_vector_type(4))) float  f32x4;

__device__ __forceinline__ ushort f2bf(float x){
  unsigned u = __float_as_uint(x);
  u = (u + 0x7FFFu + ((u >> 16) & 1u)) >> 16;
  return (ushort)u;
}
__device__ __forceinline__ float bf2f(ushort h){
  return __uint_as_float(((uint)h) << 16);
}
__device__ __forceinline__ uint pk(float a, float b){
  return (uint)f2bf(a) | ((uint)f2bf(b) << 16);
}

// Generate 128x128 bf16 DFT twiddle table into LDS (pitch TP).
// SGN=-1: fwd exp(-i 2pi nk/128); SGN=+1: inverse exp(+i 2pi nk/128).
template<int SGN>
__device__ __forceinline__ void gen_table(ushort* Fre, ushort* Fim, int t){
  int n = t >> 2, kb = (t & 3) * 32;
  #pragma unroll
  for(int q=0; q<4; q++){
    ushort8 cv, sv;
    #pragma unroll
    for(int j=0; j<8; j++){
      int k = kb + q*8 + j;
      int idx = (n*k) & 127;
      float ss, cc;
      __sincosf((float)idx * 0.049087385212340517f, &ss, &cc);  // 2pi/128
      cv[j] = f2bf(cc);
      sv[j] = f2bf(SGN < 0 ? -ss : ss);
    }
    *(ushort8*)(&Fre[n*TP + kb + q*8]) = cv;
    *(ushort8*)(&Fim[n*TP + kb + q*8]) = sv;
  }
}

// ---------------- kernel 0: fold BN, emit MFMA-fragment-packed bf16 weights --
// wb layout: shorts [0,32768)     = w1p B-frags: [(et*4+kt)*64 + l]*8 + j
//            shorts [32768,65536) = w2p A-frags: [(ot*8+kt)*64 + l]*8 + j
//            floats [32768,33024) = c1[256]; floats [33024,33152) = c2[128]
__global__ __launch_bounds__(256) void k_prep(
    const float* __restrict__ w1, const float* __restrict__ b1,
    const float* __restrict__ g1, const float* __restrict__ be1,
    const float* __restrict__ m1, const float* __restrict__ v1,
    const float* __restrict__ w2, const float* __restrict__ b2,
    const float* __restrict__ g2, const float* __restrict__ be2,
    const float* __restrict__ m2, const float* __restrict__ v2,
    float* __restrict__ wb){
  int g = blockIdx.x*256 + threadIdx.x;      // 65536 threads
  ushort* wbs = (ushort*)wb;
  if(g < 32768){
    int kt = (g >> 9) & 3, l = (g >> 3) & 63, j = g & 7;
    int et = g >> 11;
    int c = kt*32 + 8*(l>>4) + j;
    int e = et*16 + (l&15);
    float s1 = g1[e]*rsqrtf(v1[e]+1e-5f);
    wbs[g] = f2bf(w1[e*128 + c]*s1);
  } else {
    int g2i = g - 32768;
    int ot = g2i >> 12, kt = (g2i >> 9) & 7, l = (g2i >> 3) & 63, j = g2i & 7;
    int o = ot*16 + (l&15);
    int e = kt*32 + 8*(l>>4) + j;
    float s2 = g2[o]*rsqrtf(v2[o]+1e-5f);
    wbs[32768 + g2i] = f2bf(w2[o*256 + e]*s2);
  }
  if(g < 256){
    float s1 = g1[g]*rsqrtf(v1[g]+1e-5f);
    wb[32768 + g] = b1[g]*s1 + be1[g] - m1[g]*s1;
  }
  if(g < 128){
    float s2 = g2[g]*rsqrtf(v2[g]+1e-5f);
    wb[33024 + g] = b2[g]*s2 + be2[g] - m2[g]*s2;
  }
}

// ---------------- kernel 1: forward 2D DFT via MFMA + fftshift + HPF ---------
// spec[b'][c'][wd][hd] = masked shifted 2D fwd DFT (ortho 1/128 folded here).
// Step A: P[h][wd] = sum_w x[h][w] * F[wd^64][w]   (real input, strip-streamed)
// Step B: S[wd][hd] = sum_h P[h][wd] * F[hd^64][h]
__global__ __launch_bounds__(512,1) void k_fft_fwd(const float* __restrict__ x2,
                                                   uint* __restrict__ spec){
  __shared__ ushort Fre[128*TP], Fim[128*TP];
  __shared__ ushort Pre[128*TP], Pim[128*TP];   // P stored [wd][h]
  __shared__ ushort xb[2][16*TP];
  int t = threadIdx.x, l = t & 63, wv = t >> 6;
  int bid = blockIdx.x, b = bid >> 7, c = bid & 127;
  const float* src = x2 + (size_t)(b*128 + c)*PLANE;
  gen_table<-1>(Fre, Fim, t);
  int hr = t >> 5, c4 = (t & 31)*4;
  { // stage strip 0
    f32x4 v = *(const f32x4*)(src + hr*128 + c4);
    bf16x4 o;
    #pragma unroll
    for(int j=0;j<4;j++) o[j] = f2bf(v[j]);
    *(bf16x4*)(&xb[0][hr*TP + c4]) = o;
  }
  __syncthreads();
  int koff = 8*(l >> 4);
  for(int s=0; s<8; s++){
    f32x4 pf;
    if(s < 7) pf = *(const f32x4*)(src + (16*(s+1) + hr)*128 + c4);
    // step A tile: wave wv -> wd col-tile [16wv,16wv+16), rows h in strip
    int arow = (l & 15)*TP;
    int brow = (16*(wv ^ 4) + (l & 15))*TP;     // ^64 shift baked as tile^4
    f32x4 pr = {0,0,0,0}, pi = {0,0,0,0};
    #pragma unroll
    for(int kt=0; kt<4; kt++){
      short8 xa = *(const short8*)(&xb[s&1][arow + kt*32 + koff]);
      short8 fr = *(const short8*)(&Fre[brow + kt*32 + koff]);
      short8 fi = *(const short8*)(&Fim[brow + kt*32 + koff]);
      pr = __builtin_amdgcn_mfma_f32_16x16x32_bf16(xa, fr, pr, 0,0,0);
      pi = __builtin_amdgcn_mfma_f32_16x16x32_bf16(xa, fi, pi, 0,0,0);
    }
    int wd = 16*wv + (l & 15);
    int hb = 16*s + 4*(l >> 4);
    bf16x4 pr4, pi4;
    #pragma unroll
    for(int r=0;r<4;r++){ pr4[r] = f2bf(pr[r]); pi4[r] = f2bf(pi[r]); }
    *(bf16x4*)(&Pre[wd*TP + hb]) = pr4;
    *(bf16x4*)(&Pim[wd*TP + hb]) = pi4;
    if(s < 7){
      bf16x4 o;
      #pragma unroll
      for(int j=0;j<4;j++) o[j] = f2bf(pf[j]);
      *(bf16x4*)(&xb[(s+1)&1][hr*TP + c4]) = o;
    }
    __syncthreads();
  }
  // step B: wave wv owns wd-strip [16wv,16wv+16)
  int bp = (b + 8) & 15, cp = (c + 64) & 127;
  uint* dst = spec + (size_t)(bp*128 + cp)*PLANE;
  int arow2 = (16*wv + (l & 15))*TP;
  short8 ar[4], ai[4];
  #pragma unroll
  for(int kt=0; kt<4; kt++){
    ar[kt] = *(const short8*)(&Pre[arow2 + kt*32 + koff]);
    ai[kt] = *(const short8*)(&Pim[arow2 + kt*32 + koff]);
  }
  const float SC = 1.0f/128.0f;
  #pragma unroll
  for(int ct=0; ct<8; ct++){
    int brow = (16*(ct ^ 4) + (l & 15))*TP;     // hd^64 shift baked
    f32x4 sr_ = {0,0,0,0}, si_ = {0,0,0,0};
    #pragma unroll
    for(int kt=0; kt<4; kt++){
      short8 fi = *(const short8*)(&Fim[brow + kt*32 + koff]);
      sr_ = __builtin_amdgcn_mfma_f32_16x16x32_bf16(ai[kt], fi, sr_, 0,0,0);
      si_ = __builtin_amdgcn_mfma_f32_16x16x32_bf16(ar[kt], fi, si_, 0,0,0);
    }
    sr_ = -sr_;                                  // -> -sum Pim*Fim
    #pragma unroll
    for(int kt=0; kt<4; kt++){
      short8 fr = *(const short8*)(&Fre[brow + kt*32 + koff]);
      sr_ = __builtin_amdgcn_mfma_f32_16x16x32_bf16(ar[kt], fr, sr_, 0,0,0);
      si_ = __builtin_amdgcn_mfma_f32_16x16x32_bf16(ai[kt], fr, si_, 0,0,0);
    }
    int hd = 16*ct + (l & 15);
    float dh = (float)hd - 63.5f;
    float dh2 = dh*dh;
    #pragma unroll
    for(int r=0; r<4; r++){
      int wd = 16*wv + 4*(l>>4) + r;
      float dw = (float)wd - 63.5f;
      float m = (dw*dw + dh2 >= 64.0f) ? SC : 0.0f;
      dst[wd*128 + hd] = pk(sr_[r]*m, si_[r]*m);
    }
  }
}

// ---------------- kernel 2: fused 1x1conv chain via bf16 MFMA ----------------
#define XPITCH 136
#define EPITCH 264
__global__ __launch_bounds__(256,3) void k_conv(const float* __restrict__ wb,
                                                const uint* __restrict__ spec,
                                                uint* __restrict__ zo){
  __shared__ ushort xs[64*XPITCH];
  __shared__ ushort hs[64*EPITCH];
  const ushort* wbs = (const ushort*)wb;
  int bid = blockIdx.x;
  int b = bid >> 9;
  int pix0 = (bid & 511) * 32;
  const uint* sp = spec + (size_t)(b*128)*PLANE + pix0;
  int t = threadIdx.x, l = t & 63, w = t >> 6;
  {
    int p = t & 31, g = t >> 5;
    #pragma unroll
    for(int half=0; half<2; half++){
      ushort re8[8], im8[8];
      #pragma unroll
      for(int k=0;k<8;k++){
        uint u = sp[(size_t)(g*16 + half*8 + k)*PLANE + p];
        re8[k] = (ushort)u; im8[k] = (ushort)(u>>16);
      }
      *(ushort8*)(xs + p*XPITCH      + g*16 + half*8) = *(ushort8*)re8;
      *(ushort8*)(xs + (p+32)*XPITCH + g*16 + half*8) = *(ushort8*)im8;
    }
  }
  short8 bw1[4][4];
  #pragma unroll
  for(int et=0; et<4; et++)
    #pragma unroll
    for(int kt=0; kt<4; kt++)
      bw1[et][kt] = *(const short8*)(wbs + (((w*4+et)*4 + kt)*64 + l)*8);
  float c1v[4];
  #pragma unroll
  for(int et=0; et<4; et++) c1v[et] = wb[32768 + w*64 + et*16 + (l&15)];
  __syncthreads();
  #pragma unroll
  for(int mt=0; mt<4; mt++){
    short8 xa[4];
    #pragma unroll
    for(int kt=0; kt<4; kt++)
      xa[kt] = *(const short8*)(xs + (mt*16 + (l&15))*XPITCH + kt*32 + 8*(l>>4));
    f32x4 a0 = {0,0,0,0}, a1 = {0,0,0,0}, a2 = {0,0,0,0}, a3 = {0,0,0,0};
    #pragma unroll
    for(int kt=0; kt<4; kt++){
      a0 = __builtin_amdgcn_mfma_f32_16x16x32_bf16(xa[kt], bw1[0][kt], a0, 0,0,0);
      a1 = __builtin_amdgcn_mfma_f32_16x16x32_bf16(xa[kt], bw1[1][kt], a1, 0,0,0);
      a2 = __builtin_amdgcn_mfma_f32_16x16x32_bf16(xa[kt], bw1[2][kt], a2, 0,0,0);
      a3 = __builtin_amdgcn_mfma_f32_16x16x32_bf16(xa[kt], bw1[3][kt], a3, 0,0,0);
    }
    #pragma unroll
    for(int et=0; et<4; et++){
      f32x4 av = et==0?a0 : et==1?a1 : et==2?a2 : a3;
      #pragma unroll
      for(int r=0; r<4; r++){
        float h = fmaxf(av[r] + c1v[et], 0.f);
        hs[(mt*16 + (l>>4)*4 + r)*EPITCH + w*64 + et*16 + (l&15)] = f2bf(h);
      }
    }
  }
  short8 aw2[2][8];
  #pragma unroll
  for(int ot=0; ot<2; ot++)
    #pragma unroll
    for(int kt=0; kt<8; kt++)
      aw2[ot][kt] = *(const short8*)(wbs + 32768 + (((w*2+ot)*8 + kt)*64 + l)*8);
  float c2r[8];
  #pragma unroll
  for(int ot=0; ot<2; ot++)
    #pragma unroll
    for(int r=0; r<4; r++)
      c2r[ot*4+r] = wb[33024 + w*32 + ot*16 + (l>>4)*4 + r];
  __syncthreads();
  f32x4 d[2][4];
  #pragma unroll
  for(int ot=0; ot<2; ot++)
    #pragma unroll
    for(int pt=0; pt<4; pt++) d[ot][pt] = (f32x4){0,0,0,0};
  for(int kt=0; kt<8; kt++){
    short8 hb[4];
    #pragma unroll
    for(int pt=0; pt<4; pt++)
      hb[pt] = *(const short8*)(hs + (pt*16 + (l&15))*EPITCH + kt*32 + 8*(l>>4));
    #pragma unroll
    for(int ot=0; ot<2; ot++)
      #pragma unroll
      for(int pt=0; pt<4; pt++)
        d[ot][pt] = __builtin_amdgcn_mfma_f32_16x16x32_bf16(aw2[ot][kt], hb[pt], d[ot][pt], 0,0,0);
  }
  uint* zb = zo + (size_t)(b*128)*PLANE + pix0;
  #pragma unroll
  for(int ot=0; ot<2; ot++){
    #pragma unroll
    for(int pp=0; pp<2; pp++){
      #pragma unroll
      for(int r=0; r<4; r++){
        int o = w*32 + ot*16 + (l>>4)*4 + r;
        int p = pp*16 + (l&15);
        float re = d[ot][pp][r]   + c2r[ot*4+r] + bf2f(xs[p*XPITCH + o]);
        float im = d[ot][pp+2][r] + c2r[ot*4+r] + bf2f(xs[(p+32)*XPITCH + o]);
        zb[(size_t)o*PLANE + p] = pk(re, im);
      }
    }
  }
}

// ---------------- kernel 3: inverse 2D DFT via MFMA + |.| + outputs ----------
// z[wd][hd] bf16 packed (aliases out+2*NTOT, plane-aligned).
// Step A: T[wd][nh] = sum_hd Z[wd][hd] * G[nh][hd]   (strip-streamed over wd)
// Step B: S[nh][nw] = sum_wd T[wd][nh] * G[nw][wd];  h = |S| / 128
__global__ __launch_bounds__(512,1) void k_ifft_out(const uint* z,
                                                    const float* __restrict__ xin1,
                                                    const float* __restrict__ xin2,
                                                    float* out){
  __shared__ ushort Gre[128*TP], Gim[128*TP];
  __shared__ ushort Tre[128*TP], Tim[128*TP];   // T stored [nh][wd]
  __shared__ ushort zbr[2][16*TP], zbi[2][16*TP];
  int t = threadIdx.x, l = t & 63, wv = t >> 6;
  int bid = blockIdx.x, b = bid >> 7, o = bid & 127;
  size_t plane = (size_t)(b*128 + o)*PLANE;
  const uint* zp = z + plane;
  gen_table<1>(Gre, Gim, t);
  int rr = t >> 5, c4 = (t & 31)*4;
  { // stage strip 0 (wd rows 0..15)
    u32x4 u = *(const u32x4*)(zp + rr*128 + c4);
    bf16x4 ur, ui;
    #pragma unroll
    for(int j=0;j<4;j++){ ur[j] = (ushort)u[j]; ui[j] = (ushort)(u[j]>>16); }
    *(bf16x4*)(&zbr[0][rr*TP + c4]) = ur;
    *(bf16x4*)(&zbi[0][rr*TP + c4]) = ui;
  }
  __syncthreads();
  int koff = 8*(l >> 4);
  for(int s=0; s<8; s++){
    u32x4 pf;
    if(s < 7) pf = *(const u32x4*)(zp + (16*(s+1) + rr)*128 + c4);
    // step A tile: wave wv -> nh col-tile [16wv,+16), rows wd in strip
    int arow = (l & 15)*TP;
    int brow = (16*wv + (l & 15))*TP;
    short8 zr[4], zi[4], gr[4], gi[4];
    #pragma unroll
    for(int kt=0; kt<4; kt++){
      zr[kt] = *(const short8*)(&zbr[s&1][arow + kt*32 + koff]);
      zi[kt] = *(const short8*)(&zbi[s&1][arow + kt*32 + koff]);
      gr[kt] = *(const short8*)(&Gre[brow + kt*32 + koff]);
      gi[kt] = *(const short8*)(&Gim[brow + kt*32 + koff]);
    }
    f32x4 tr = {0,0,0,0}, ti = {0,0,0,0};
    #pragma unroll
    for(int kt=0; kt<4; kt++) tr = __builtin_amdgcn_mfma_f32_16x16x32_bf16(zi[kt], gi[kt], tr, 0,0,0);
    tr = -tr;                                    // -> -sum Zim*Gim
    #pragma unroll
    for(int kt=0; kt<4; kt++) tr = __builtin_amdgcn_mfma_f32_16x16x32_bf16(zr[kt], gr[kt], tr, 0,0,0);
    #pragma unroll
    for(int kt=0; kt<4; kt++){
      ti = __builtin_amdgcn_mfma_f32_16x16x32_bf16(zr[kt], gi[kt], ti, 0,0,0);
      ti = __builtin_amdgcn_mfma_f32_16x16x32_bf16(zi[kt], gr[kt], ti, 0,0,0);
    }
    int nh = 16*wv + (l & 15);
    int wdb = 16*s + 4*(l >> 4);
    bf16x4 t4r, t4i;
    #pragma unroll
    for(int r=0;r<4;r++){ t4r[r] = f2bf(tr[r]); t4i[r] = f2bf(ti[r]); }
    *(bf16x4*)(&Tre[nh*TP + wdb]) = t4r;
    *(bf16x4*)(&Tim[nh*TP + wdb]) = t4i;
    if(s < 7){
      bf16x4 ur, ui;
      #pragma unroll
      for(int j=0;j<4;j++){ ur[j] = (ushort)pf[j]; ui[j] = (ushort)(pf[j]>>16); }
      *(bf16x4*)(&zbr[(s+1)&1][rr*TP + c4]) = ur;
      *(bf16x4*)(&zbi[(s+1)&1][rr*TP + c4]) = ui;
    }
    __syncthreads();
  }
  // step B: wave wv owns nh-strip [16wv,+16)
  int arow2 = (16*wv + (l & 15))*TP;
  short8 ar[4], ai[4];
  #pragma unroll
  for(int kt=0; kt<4; kt++){
    ar[kt] = *(const short8*)(&Tre[arow2 + kt*32 + koff]);
    ai[kt] = *(const short8*)(&Tim[arow2 + kt*32 + koff]);
  }
  const float SC = 1.0f/128.0f;
  #pragma unroll
  for(int ct=0; ct<8; ct++){
    int brow = (16*ct + (l & 15))*TP;
    f32x4 sr_ = {0,0,0,0}, si_ = {0,0,0,0};
    #pragma unroll
    for(int kt=0; kt<4; kt++){
      short8 gi = *(const short8*)(&Gim[brow + kt*32 + koff]);
      sr_ = __builtin_amdgcn_mfma_f32_16x16x32_bf16(ai[kt], gi, sr_, 0,0,0);
      si_ = __builtin_amdgcn_mfma_f32_16x16x32_bf16(ar[kt], gi, si_, 0,0,0);
    }
    sr_ = -sr_;                                  // -> -sum Tim*Gim
    #pragma unroll
    for(int kt=0; kt<4; kt++){
      short8 gr = *(const short8*)(&Gre[brow + kt*32 + koff]);
      sr_ = __builtin_amdgcn_mfma_f32_16x16x32_bf16(ar[kt], gr, sr_, 0,0,0);
      si_ = __builtin_amdgcn_mfma_f32_16x16x32_bf16(ai[kt], gr, si_, 0,0,0);
    }
    #pragma unroll
    for(int r=0; r<4; r++){
      int nh = 16*wv + 4*(l>>4) + r;
      int nw = 16*ct + (l & 15);
      size_t idx = plane + (size_t)nh*128 + nw;
      float h = sqrtf(sr_[r]*sr_[r] + si_[r]*si_[r]) * SC;
      float u = xin1[idx], v = xin2[idx];
      out[idx] = u*h + u;
      out[NTOT + idx] = v*h + v;
      out[2u*NTOT + idx] = h;
    }
  }
}

extern "C" void kernel_launch(void* const* d_in, const int* in_sizes, int n_in,
                              void* d_out, int out_size, void* d_ws, size_t ws_size,
                              hipStream_t stream){
  (void)in_sizes; (void)n_in; (void)d_ws; (void)ws_size; (void)out_size;
  const float* x1  = (const float*)d_in[0];
  const float* x2  = (const float*)d_in[1];
  const float* w1  = (const float*)d_in[2];
  const float* b1  = (const float*)d_in[3];
  const float* g1  = (const float*)d_in[4];
  const float* be1 = (const float*)d_in[5];
  const float* m1  = (const float*)d_in[6];
  const float* v1  = (const float*)d_in[7];
  const float* w2  = (const float*)d_in[8];
  const float* b2  = (const float*)d_in[9];
  const float* g2  = (const float*)d_in[10];
  const float* be2 = (const float*)d_in[11];
  const float* m2  = (const float*)d_in[12];
  const float* v2  = (const float*)d_in[13];
  float* out = (float*)d_out;
  float* wb   = out;                       // slot0: weights (dead after conv)
  uint*  spec = (uint*)(out + NTOT);       // slot1: bf16 spectrum (dead after conv)
  uint*  z    = (uint*)(out + 2u*NTOT);    // slot2: bf16 z, plane-aliased with hx
  hipLaunchKernelGGL(k_prep,     dim3(256),  dim3(256), 0, stream,
                     w1,b1,g1,be1,m1,v1,w2,b2,g2,be2,m2,v2, wb);
  hipLaunchKernelGGL(k_fft_fwd,  dim3(2048), dim3(512), 0, stream, x2, spec);
  hipLaunchKernelGGL(k_conv,     dim3(8192), dim3(256), 0, stream, wb, spec, z);
  hipLaunchKernelGGL(k_ifft_out, dim3(2048), dim3(512), 0, stream, z, x1, x2, out);
}